// Round 23
// baseline (39.805 us; speedup 1.0000x reference)
//
#include <hip/hip_runtime.h>
#include <hip/hip_bf16.h>

// Depth-4 path signature, C=10, L=64, B=2048 — MFMA formulation (R23).
// Closed form (validated R8-R22, absmax 5.25 vs thr 12.16):
//   P_t = exclusive prefix of dx;  R_t[l] = S1[l] - P_{t+1}[l]
//   per (i,j): s2 serial chain; u2_t, v2_t level-2 scalars
//   S4[ij,kl] = sum_t v2_t*(dx_t[k]*R_t[l]) + sum_t u2_t*(dx_t[k]*dx_t[l]/2)
//   S3[ij,k]  = sum_t v2_t*dx_t[k]
// R23 vs R22 (best, 33.8us): SINGLE K=128 GEMM pass, 3 barriers (was 5 +
// two passes + mid-rebuild). A(100x128)=[V2|U2], B(110x128)=[dx ox R | dx ;
// dx ox dx/2 | 0], all built in ONE phase (A-chain waves 0-1, B tasks waves
// 2-7). k-chunk order V0,V1,U0,U1 preserves R22's exact FP accumulation
// order -> absmax identical. KS=128 shorts = 256B stride == 0 mod 128B so
// the granule swizzle remains an exact bank permutation (R11-validated).
// LDS 59.2KB -> 2 blocks/CU; bet: shorter critical path beats residency.

typedef short short8 __attribute__((ext_vector_type(8)));
typedef float f2 __attribute__((ext_vector_type(2)));
typedef float f4 __attribute__((ext_vector_type(4)));
typedef float f32x4 __attribute__((ext_vector_type(4)));
typedef unsigned int uint4v __attribute__((ext_vector_type(4)));

constexpr int C = 10, L = 64, T = 63;          // T = L-1 steps
constexpr int OUTSZ = 10 + 100 + 1000 + 10000; // 11110
constexpr int SP = 68;                         // dxT/PsT row stride (fp32)
constexpr int KS = 128;                        // A/B row stride in shorts (256B)

__device__ __forceinline__ unsigned packbf(float lo, float hi) {  // v_cvt_pk_bf16_f32
  union { __hip_bfloat162 h; unsigned u; } cv;
  cv.h = __float22bfloat162_rn(make_float2(lo, hi));
  return cv.u;
}
__device__ __forceinline__ int swz(int row, int k) {  // short idx, 16B-granule XOR
  return row * KS + ((((k >> 3) ^ (row & 7)) << 3) | (k & 7));
}

__global__ __launch_bounds__(512, 4) void sig4_kernel(
    const float* __restrict__ x, float* __restrict__ out)
{
  __shared__ __align__(16) unsigned char smem_raw[59200];
  unsigned short* Ab = (unsigned short*)smem_raw;            // [V2|U2]: 25600B
  unsigned short* Bb = (unsigned short*)(smem_raw + 25600);  // 28160B
  float* dxT = (float*)(smem_raw + 53760);                   // 10*68 f = 2720B
  float* PsT = (float*)(smem_raw + 56480);                   // 10*68 f = 2720B

  const int t = threadIdx.x;
  const int w = t >> 6, lane = t & 63;
  const float* __restrict__ xb = x + (size_t)blockIdx.x * (C * L);
  float* __restrict__ ob = out + (size_t)blockIdx.x * OUTSZ;

  // ---- stage: dxT (transposed, zero-padded) from global ----
  for (int i = t; i < C * SP; i += 512) {
    int c = i / SP, s = i - c * SP;
    float v = 0.f;
    if (s < T) v = xb[c * L + s + 1] - xb[c * L + s];
    dxT[i] = v;
  }
  __syncthreads();
  // exclusive prefix P per channel (one channel per wave); PsT[c][63] = S1[c]
  for (int c = w; c < C; c += 8) {
    float v = (lane > 0) ? dxT[c * SP + lane - 1] : 0.f;
    #pragma unroll
    for (int d = 1; d < 64; d <<= 1) {
      float y = __shfl_up(v, d);
      if (lane >= d) v += y;
    }
    PsT[c * SP + lane] = v;
  }
  if (t < 40) PsT[(t >> 2) * SP + 64 + (t & 3)] = 0.f;  // zero pad cols 64..67
  __syncthreads();

  // ---- ONE build phase: A-chain (waves 0-1) || B (waves 2-7) ----
  if (t < 100) {
    const int i_ = t / 10, j_ = t - (t / 10) * 10;
    const float* dip = dxT + i_ * SP;
    const float* pp  = PsT + i_ * SP;
    const float* djp = dxT + j_ * SP;
    float s2 = 0.f;
    #pragma unroll
    for (int ch = 0; ch < 8; ++ch) {
      f4 d0 = *(const f4*)(dip + ch * 8), d1 = *(const f4*)(dip + ch * 8 + 4);
      f4 p0 = *(const f4*)(pp  + ch * 8), p1 = *(const f4*)(pp  + ch * 8 + 4);
      f4 e0 = *(const f4*)(djp + ch * 8), e1 = *(const f4*)(djp + ch * 8 + 4);
      float di[8] = {d0.x, d0.y, d0.z, d0.w, d1.x, d1.y, d1.z, d1.w};
      float pv[8] = {p0.x, p0.y, p0.z, p0.w, p1.x, p1.y, p1.z, p1.w};
      float dj[8] = {e0.x, e0.y, e0.z, e0.w, e1.x, e1.y, e1.z, e1.w};
      float bu[8], bv[8], zz[8];
      #pragma unroll
      for (int e = 0; e < 8; ++e) {            // pointwise (s=63: all zero)
        bu[e] = fmaf(di[e], 0.25f, pv[e]) * (dj[e] * (1.f / 3.f));
        bv[e] = fmaf(di[e], (1.f / 3.f), pv[e]) * (dj[e] * 0.5f);
        zz[e] = fmaf(di[e], 0.5f, pv[e]) * dj[e];
      }
      float u2v[8], v2v[8];
      #pragma unroll
      for (int e = 0; e < 8; ++e) {            // serial: 1 dependent add/step
        u2v[e] = bu[e] + s2;
        v2v[e] = bv[e] + s2;
        s2 += zz[e];
      }
      uint4v vp, up;
      #pragma unroll
      for (int q = 0; q < 4; ++q) {
        vp[q] = packbf(v2v[2 * q], v2v[2 * q + 1]);
        up[q] = packbf(u2v[2 * q], u2v[2 * q + 1]);
      }
      *(uint4v*)&Ab[swz(t, ch * 8)]      = vp;   // V2 -> k 0..63
      *(uint4v*)&Ab[swz(t, 64 + ch * 8)] = up;   // U2 -> k 64..127
    }
    ob[10 + t] = s2;                           // S2 (fp32)
    if (j_ == 0) ob[i_] = PsT[i_ * SP + 63];   // S1
  } else if (t >= 128) {
    const int q = t - 128;                     // 384 lanes, 1760 tasks
    for (int task = q; task < 110 * 16; task += 384) {
      const int col = task >> 4, ch = task & 15;   // ch 0-7: B0, 8-15: B1
      const int base = (ch & 7) * 8;
      float bval[8];
      if (ch < 8) {
        if (col < 100) {                       // dx_k * R_k
          const int k2 = col / 10, l2 = col - (col / 10) * 10;
          const float* dk = dxT + k2 * SP;
          const float* pl = PsT + l2 * SP;
          const float S1l = pl[63];
          f4 d0 = *(const f4*)(dk + base), d1 = *(const f4*)(dk + base + 4);
          f4 pa = *(const f4*)(pl + base + 1), pb = *(const f4*)(pl + base + 5);
          float dv[8] = {d0.x, d0.y, d0.z, d0.w, d1.x, d1.y, d1.z, d1.w};
          float Pn[8] = {pa.x, pa.y, pa.z, pa.w, pb.x, pb.y, pb.z, pb.w};
          #pragma unroll
          for (int e = 0; e < 8; ++e) bval[e] = dv[e] * (S1l - Pn[e]);
        } else {                               // S3 cols: dx
          const float* dk = dxT + (col - 100) * SP;
          f4 d0 = *(const f4*)(dk + base), d1 = *(const f4*)(dk + base + 4);
          bval[0] = d0.x; bval[1] = d0.y; bval[2] = d0.z; bval[3] = d0.w;
          bval[4] = d1.x; bval[5] = d1.y; bval[6] = d1.z; bval[7] = d1.w;
        }
      } else {
        if (col < 100) {                       // dx_k * dx_l / 2
          const int k2 = col / 10, l2 = col - (col / 10) * 10;
          const float* dk = dxT + k2 * SP;
          const float* dl = dxT + l2 * SP;
          f4 a0 = *(const f4*)(dk + base), a1 = *(const f4*)(dk + base + 4);
          f4 c0 = *(const f4*)(dl + base), c1 = *(const f4*)(dl + base + 4);
          bval[0] = a0.x * c0.x * 0.5f; bval[1] = a0.y * c0.y * 0.5f;
          bval[2] = a0.z * c0.z * 0.5f; bval[3] = a0.w * c0.w * 0.5f;
          bval[4] = a1.x * c1.x * 0.5f; bval[5] = a1.y * c1.y * 0.5f;
          bval[6] = a1.z * c1.z * 0.5f; bval[7] = a1.w * c1.w * 0.5f;
        } else {
          #pragma unroll
          for (int e = 0; e < 8; ++e) bval[e] = 0.f;
        }
      }
      const int kbase = (ch < 8) ? base : (64 + base);
      uint4v pk;
      #pragma unroll
      for (int qq = 0; qq < 4; ++qq) pk[qq] = packbf(bval[2 * qq], bval[2 * qq + 1]);
      *(uint4v*)&Bb[swz(col, kbase)] = pk;
    }
  }
  __syncthreads();

  // ---- single GEMM pass (K=128) + epilogue, one rt-strip per wave ----
  if (w < 7) {
    const int lm = lane & 15, lg = lane >> 4;
    const int arow = w * 16 + lm;
    short8 a[4];
    #pragma unroll
    for (int ks = 0; ks < 4; ++ks)
      a[ks] = (arow < 100) ? *(const short8*)&Ab[swz(arow, ks * 32 + lg * 8)]
                           : short8{0, 0, 0, 0, 0, 0, 0, 0};
    f32x4 acc[7];
    #pragma unroll
    for (int ct = 0; ct < 7; ++ct) {
      const int bcol = ct * 16 + lm;
      acc[ct] = f32x4{0.f, 0.f, 0.f, 0.f};
      #pragma unroll
      for (int ks = 0; ks < 4; ++ks) {         // order V0,V1,U0,U1 = R22 FP order
        short8 bf = (bcol < 110)
            ? *(const short8*)&Bb[swz(bcol, ks * 32 + lg * 8)]
            : short8{0, 0, 0, 0, 0, 0, 0, 0};
        acc[ct] = __builtin_amdgcn_mfma_f32_16x16x32_bf16(bf, a[ks], acc[ct], 0, 0, 0);
      }
    }

    const int row = w * 16 + lm;               // output ij-row (transposed C)
    if (row < 100) {
      float* rowp4 = ob + 1110 + row * 100;
      float* rowp3 = ob + 110 + row * 10;
      #pragma unroll
      for (int ct = 0; ct < 7; ++ct) {
        const int colbase = ct * 16 + lg * 4;  // 4 consecutive output cols
        f2 lo = {acc[ct][0], acc[ct][1]};
        f2 hi = {acc[ct][2], acc[ct][3]};
        if (colbase < 100) {
          *(f2*)(rowp4 + colbase) = lo;
          *(f2*)(rowp4 + colbase + 2) = hi;
        } else if (colbase < 110) {
          *(f2*)(rowp3 + (colbase - 100)) = lo;
          if (colbase < 108) *(f2*)(rowp3 + (colbase - 98)) = hi;
        }
      }
    }
  }
}

extern "C" void kernel_launch(void* const* d_in, const int* in_sizes, int n_in,
                              void* d_out, int out_size, void* d_ws, size_t ws_size,
                              hipStream_t stream) {
  const float* x = (const float*)d_in[0];
  float* out = (float*)d_out;
  const int batch = in_sizes[0] / (C * L);   // 2048
  sig4_kernel<<<dim3(batch), dim3(512), 0, stream>>>(x, out);
}

// Round 24
// 32.966 us; speedup vs baseline: 1.2075x; 1.2075x over previous
//
#include <hip/hip_runtime.h>
#include <hip/hip_bf16.h>

// Depth-4 path signature, C=10, L=64, B=2048 — MFMA formulation (R24).
// Closed form (validated R8-R23, absmax 5.25 vs thr 12.16):
//   P_t = exclusive prefix of dx;  R_t[l] = S1[l] - P_{t+1}[l]
//   per (i,j): s2 serial chain; u2_t, v2_t level-2 scalars
//   S4[ij,kl] = sum_t v2_t*(dx_t[k]*R_t[l]) + sum_t u2_t*(dx_t[k]*dx_t[l]/2)
//   S3[ij,k]  = sum_t v2_t*dx_t[k]
// R24 = R23's 3-barrier single-build pipeline at R22's 3-block residency.
// Enabler: B1 = dx ox dx /2 is SYMMETRIC in (k2,l2) -> store only the 55
// triangular rows (7040B, not 14080B); its S3 cols are exactly 0 (zero
// fragments in GEMM1). All of A(V2,U2), B0, B1 built in ONE phase; GEMM0
// (V2 x B0) and GEMM1 (U2 x B1tri) run back-to-back with NO barrier
// (read-only LDS). LDS 52160B -> 3 blocks/CU (R23's 59.2KB -> 2 was the
// regression cause). MFMA order per acc = V0,V1,U0,U1 = R22's exact FP
// order -> absmax identical.

typedef short short8 __attribute__((ext_vector_type(8)));
typedef float f2 __attribute__((ext_vector_type(2)));
typedef float f4 __attribute__((ext_vector_type(4)));
typedef float f32x4 __attribute__((ext_vector_type(4)));
typedef unsigned int uint4v __attribute__((ext_vector_type(4)));

constexpr int C = 10, L = 64, T = 63;          // T = L-1 steps
constexpr int OUTSZ = 10 + 100 + 1000 + 10000; // 11110
constexpr int SP = 68;                         // dxT/PsT row stride (fp32)
constexpr int KS = 64;                         // A/B row stride in shorts (128B)

__device__ __forceinline__ unsigned packbf(float lo, float hi) {  // v_cvt_pk_bf16_f32
  union { __hip_bfloat162 h; unsigned u; } cv;
  cv.h = __float22bfloat162_rn(make_float2(lo, hi));
  return cv.u;
}
__device__ __forceinline__ int swz(int row, int k) {  // short idx, 16B-granule XOR
  return row * KS + ((((k >> 3) ^ (row & 7)) << 3) | (k & 7));
}

__global__ __launch_bounds__(512, 6) void sig4_kernel(
    const float* __restrict__ x, float* __restrict__ out)
{
  __shared__ __align__(16) unsigned char smem_raw[52160];
  unsigned short* Ab  = (unsigned short*)smem_raw;            // V2: 12800B
  unsigned short* Ub  = (unsigned short*)(smem_raw + 12800);  // U2: 12800B
  unsigned short* B0b = (unsigned short*)(smem_raw + 25600);  // 110*64 sh = 14080B
  unsigned short* B1b = (unsigned short*)(smem_raw + 39680);  // 55*64 sh = 7040B
  float* dxT = (float*)(smem_raw + 46720);                    // 10*68 f = 2720B
  float* PsT = (float*)(smem_raw + 49440);                    // 10*68 f = 2720B

  const int t = threadIdx.x;
  const int w = t >> 6, lane = t & 63;
  const float* __restrict__ xb = x + (size_t)blockIdx.x * (C * L);
  float* __restrict__ ob = out + (size_t)blockIdx.x * OUTSZ;

  // ---- stage: dxT (transposed, zero-padded) from global ----
  for (int i = t; i < C * SP; i += 512) {
    int c = i / SP, s = i - c * SP;
    float v = 0.f;
    if (s < T) v = xb[c * L + s + 1] - xb[c * L + s];
    dxT[i] = v;
  }
  __syncthreads();
  // exclusive prefix P per channel (one channel per wave); PsT[c][63] = S1[c]
  for (int c = w; c < C; c += 8) {
    float v = (lane > 0) ? dxT[c * SP + lane - 1] : 0.f;
    #pragma unroll
    for (int d = 1; d < 64; d <<= 1) {
      float y = __shfl_up(v, d);
      if (lane >= d) v += y;
    }
    PsT[c * SP + lane] = v;
  }
  if (t < 40) PsT[(t >> 2) * SP + 64 + (t & 3)] = 0.f;  // zero pad cols 64..67
  __syncthreads();

  // ---- ONE build phase: A-chain (t<100) || B0+B1 tasks (t>=128) ----
  if (t < 100) {
    const int i_ = t / 10, j_ = t - (t / 10) * 10;
    const float* dip = dxT + i_ * SP;
    const float* pp  = PsT + i_ * SP;
    const float* djp = dxT + j_ * SP;
    float s2 = 0.f;
    #pragma unroll
    for (int ch = 0; ch < 8; ++ch) {
      f4 d0 = *(const f4*)(dip + ch * 8), d1 = *(const f4*)(dip + ch * 8 + 4);
      f4 p0 = *(const f4*)(pp  + ch * 8), p1 = *(const f4*)(pp  + ch * 8 + 4);
      f4 e0 = *(const f4*)(djp + ch * 8), e1 = *(const f4*)(djp + ch * 8 + 4);
      float di[8] = {d0.x, d0.y, d0.z, d0.w, d1.x, d1.y, d1.z, d1.w};
      float pv[8] = {p0.x, p0.y, p0.z, p0.w, p1.x, p1.y, p1.z, p1.w};
      float dj[8] = {e0.x, e0.y, e0.z, e0.w, e1.x, e1.y, e1.z, e1.w};
      float bu[8], bv[8], zz[8];
      #pragma unroll
      for (int e = 0; e < 8; ++e) {            // pointwise (s=63: all zero)
        bu[e] = fmaf(di[e], 0.25f, pv[e]) * (dj[e] * (1.f / 3.f));
        bv[e] = fmaf(di[e], (1.f / 3.f), pv[e]) * (dj[e] * 0.5f);
        zz[e] = fmaf(di[e], 0.5f, pv[e]) * dj[e];
      }
      float u2v[8], v2v[8];
      #pragma unroll
      for (int e = 0; e < 8; ++e) {            // serial: 1 dependent add/step
        u2v[e] = bu[e] + s2;
        v2v[e] = bv[e] + s2;
        s2 += zz[e];
      }
      uint4v vp, up;
      #pragma unroll
      for (int q = 0; q < 4; ++q) {
        vp[q] = packbf(v2v[2 * q], v2v[2 * q + 1]);
        up[q] = packbf(u2v[2 * q], u2v[2 * q + 1]);
      }
      *(uint4v*)&Ab[swz(t, ch * 8)] = vp;
      *(uint4v*)&Ub[swz(t, ch * 8)] = up;
    }
    ob[10 + t] = s2;                           // S2 (fp32)
    if (j_ == 0) ob[i_] = PsT[i_ * SP + 63];   // S1
  } else if (t >= 128) {
    const int q = t - 128;                     // 384 lanes; 880 B0 + 440 B1 tasks
    for (int tt = q; tt < 1320; tt += 384) {
      if (tt < 880) {                          // ---- B0 ----
        const int col = tt >> 3, ch = tt & 7, base = ch * 8;
        float bval[8];
        if (col < 100) {                       // dx_k * R_k
          const int k2 = col / 10, l2 = col - (col / 10) * 10;
          const float* dk = dxT + k2 * SP;
          const float* pl = PsT + l2 * SP;
          const float S1l = pl[63];
          f4 d0 = *(const f4*)(dk + base), d1 = *(const f4*)(dk + base + 4);
          f4 pa = *(const f4*)(pl + base), pb = *(const f4*)(pl + base + 4);
          f4 pc = *(const f4*)(pl + base + 8);   // pad cols zeroed, safe
          float dv[8] = {d0.x, d0.y, d0.z, d0.w, d1.x, d1.y, d1.z, d1.w};
          float Pn[8] = {pa.y, pa.z, pa.w, pb.x, pb.y, pb.z, pb.w, pc.x};
          #pragma unroll
          for (int e = 0; e < 8; ++e) bval[e] = dv[e] * (S1l - Pn[e]);
        } else {                               // S3 cols: dx
          const float* dk = dxT + (col - 100) * SP;
          f4 d0 = *(const f4*)(dk + base), d1 = *(const f4*)(dk + base + 4);
          bval[0] = d0.x; bval[1] = d0.y; bval[2] = d0.z; bval[3] = d0.w;
          bval[4] = d1.x; bval[5] = d1.y; bval[6] = d1.z; bval[7] = d1.w;
        }
        uint4v pk;
        #pragma unroll
        for (int qq = 0; qq < 4; ++qq) pk[qq] = packbf(bval[2 * qq], bval[2 * qq + 1]);
        *(uint4v*)&B0b[swz(col, base)] = pk;
      } else {                                 // ---- B1 (triangular) ----
        const int idx = tt - 880;
        const int col = idx >> 3, ch = idx & 7, base = ch * 8;
        float fs = sqrtf(8.f * (float)col + 1.f);
        int hi = (int)((fs - 1.f) * 0.5f);
        int tri = (hi * (hi + 1)) >> 1;
        if (col < tri) { --hi; tri = (hi * (hi + 1)) >> 1; }
        const int lo = col - tri;
        const float* dk = dxT + hi * SP;
        const float* dl = dxT + lo * SP;
        f4 a0 = *(const f4*)(dk + base), a1 = *(const f4*)(dk + base + 4);
        f4 c0 = *(const f4*)(dl + base), c1 = *(const f4*)(dl + base + 4);
        float bval[8] = {a0.x * c0.x * 0.5f, a0.y * c0.y * 0.5f,
                         a0.z * c0.z * 0.5f, a0.w * c0.w * 0.5f,
                         a1.x * c1.x * 0.5f, a1.y * c1.y * 0.5f,
                         a1.z * c1.z * 0.5f, a1.w * c1.w * 0.5f};
        uint4v pk;
        #pragma unroll
        for (int qq = 0; qq < 4; ++qq) pk[qq] = packbf(bval[2 * qq], bval[2 * qq + 1]);
        *(uint4v*)&B1b[swz(col, base)] = pk;
      }
    }
  }
  __syncthreads();

  // ---- GEMM0 + GEMM1 back-to-back (read-only LDS, no barrier) ----
  if (w < 7) {
    const int lm = lane & 15, lg = lane >> 4;
    const int arow = w * 16 + lm;
    const short8 zf = {0, 0, 0, 0, 0, 0, 0, 0};
    short8 aV0 = (arow < 100) ? *(const short8*)&Ab[swz(arow, lg * 8)] : zf;
    short8 aV1 = (arow < 100) ? *(const short8*)&Ab[swz(arow, 32 + lg * 8)] : zf;
    short8 aU0 = (arow < 100) ? *(const short8*)&Ub[swz(arow, lg * 8)] : zf;
    short8 aU1 = (arow < 100) ? *(const short8*)&Ub[swz(arow, 32 + lg * 8)] : zf;
    f32x4 acc[7];
    #pragma unroll
    for (int ct = 0; ct < 7; ++ct) {
      const int bcol = ct * 16 + lm;
      short8 b00 = (bcol < 110) ? *(const short8*)&B0b[swz(bcol, lg * 8)] : zf;
      short8 b01 = (bcol < 110) ? *(const short8*)&B0b[swz(bcol, 32 + lg * 8)] : zf;
      short8 b10 = zf, b11 = zf;
      if (bcol < 100) {
        const int k2 = bcol / 10, l2 = bcol - k2 * 10;
        const int hi = (k2 > l2) ? k2 : l2;
        const int lo = (k2 > l2) ? l2 : k2;
        const int crow = ((hi * (hi + 1)) >> 1) + lo;
        b10 = *(const short8*)&B1b[swz(crow, lg * 8)];
        b11 = *(const short8*)&B1b[swz(crow, 32 + lg * 8)];
      }
      acc[ct] = f32x4{0.f, 0.f, 0.f, 0.f};
      acc[ct] = __builtin_amdgcn_mfma_f32_16x16x32_bf16(b00, aV0, acc[ct], 0, 0, 0);
      acc[ct] = __builtin_amdgcn_mfma_f32_16x16x32_bf16(b01, aV1, acc[ct], 0, 0, 0);
      acc[ct] = __builtin_amdgcn_mfma_f32_16x16x32_bf16(b10, aU0, acc[ct], 0, 0, 0);
      acc[ct] = __builtin_amdgcn_mfma_f32_16x16x32_bf16(b11, aU1, acc[ct], 0, 0, 0);
    }

    // ---- epilogue: transposed acc -> per-lane contiguous f2 stores ----
    const int row = w * 16 + lm;               // output ij-row
    if (row < 100) {
      float* rowp4 = ob + 1110 + row * 100;
      float* rowp3 = ob + 110 + row * 10;
      #pragma unroll
      for (int ct = 0; ct < 7; ++ct) {
        const int colbase = ct * 16 + lg * 4;  // 4 consecutive output cols
        f2 lo2 = {acc[ct][0], acc[ct][1]};
        f2 hi2 = {acc[ct][2], acc[ct][3]};
        if (colbase < 100) {
          *(f2*)(rowp4 + colbase) = lo2;
          *(f2*)(rowp4 + colbase + 2) = hi2;
        } else if (colbase < 110) {
          *(f2*)(rowp3 + (colbase - 100)) = lo2;
          if (colbase < 108) *(f2*)(rowp3 + (colbase - 98)) = hi2;
        }
      }
    }
  }
}

extern "C" void kernel_launch(void* const* d_in, const int* in_sizes, int n_in,
                              void* d_out, int out_size, void* d_ws, size_t ws_size,
                              hipStream_t stream) {
  const float* x = (const float*)d_in[0];
  float* out = (float*)d_out;
  const int batch = in_sizes[0] / (C * L);   // 2048
  sig4_kernel<<<dim3(batch), dim3(512), 0, stream>>>(x, out);
}

// Round 25
// 30.676 us; speedup vs baseline: 1.2976x; 1.0746x over previous
//
#include <hip/hip_runtime.h>
#include <hip/hip_bf16.h>

// Depth-4 path signature, C=10, L=64, B=2048 — MFMA formulation (R25).
// Closed form (validated R8-R24, absmax 5.25 vs thr 12.16):
//   P_t = exclusive prefix of dx;  R_t[l] = S1[l] - P_{t+1}[l]
//   per (i,j): s2 serial chain; u2_t, v2_t level-2 scalars
//   S4[ij,kl] = sum_t v2_t*(dx_t[k]*R_t[l]) + sum_t u2_t*(dx_t[k]*dx_t[l]/2)
//   S3[ij,k]  = sum_t v2_t*dx_t[k]
// R25 vs R24 (best, 33.0us): B is never materialized. GEMM re-mapped so each
// wave owns ONE B column-strip (bcol = w*16+lm fixed per lane) and loops over
// the 7 A row-strips -> each lane computes its 4 B fragments ONCE in
// registers from dxT/P1T/PsT (12 f4 reads + ~60 VALU), zero redundancy.
// P1T = shifted prefix (P[s+1]) keeps reads 16B-aligned. acc stored per-rt
// inside the loop (4 transient VGPRs; stores overlap MFMA). LDS 52.2 ->
// 33.8KB -> 4 blocks/CU (32 waves/CU) under __launch_bounds__(512,8)
// (VGPR must stay <=64 — the 8-waves/SIMD cliff). MFMA order V0,V1,U0,U1
// and identical packbf -> absmax unchanged.

typedef short short8 __attribute__((ext_vector_type(8)));
typedef float f2 __attribute__((ext_vector_type(2)));
typedef float f4 __attribute__((ext_vector_type(4)));
typedef float f32x4 __attribute__((ext_vector_type(4)));
typedef unsigned int uint4v __attribute__((ext_vector_type(4)));

constexpr int C = 10, L = 64, T = 63;          // T = L-1 steps
constexpr int OUTSZ = 10 + 100 + 1000 + 10000; // 11110
constexpr int SP = 68;                         // dxT/PsT/P1T row stride (fp32)
constexpr int KS = 64;                         // A row stride in shorts (128B)

__device__ __forceinline__ unsigned packbf(float lo, float hi) {  // v_cvt_pk_bf16_f32
  union { __hip_bfloat162 h; unsigned u; } cv;
  cv.h = __float22bfloat162_rn(make_float2(lo, hi));
  return cv.u;
}
__device__ __forceinline__ int swz(int row, int k) {  // short idx, 16B-granule XOR
  return row * KS + ((((k >> 3) ^ (row & 7)) << 3) | (k & 7));
}
union frag_cast { uint4v u; short8 s; };

__global__ __launch_bounds__(512, 8) void sig4_kernel(
    const float* __restrict__ x, float* __restrict__ out)
{
  __shared__ __align__(16) unsigned char smem_raw[33760];
  unsigned short* Ab = (unsigned short*)smem_raw;            // V2: 12800B
  unsigned short* Ub = (unsigned short*)(smem_raw + 12800);  // U2: 12800B
  float* dxT = (float*)(smem_raw + 25600);                   // 10*68 f = 2720B
  float* PsT = (float*)(smem_raw + 28320);                   // 2720B
  float* P1T = (float*)(smem_raw + 31040);                   // 2720B (P[s+1])

  const int t = threadIdx.x;
  const int w = t >> 6, lane = t & 63;
  const float* __restrict__ xb = x + (size_t)blockIdx.x * (C * L);
  float* __restrict__ ob = out + (size_t)blockIdx.x * OUTSZ;

  // ---- stage: dxT (transposed, zero-padded) from global ----
  for (int i = t; i < C * SP; i += 512) {
    int c = i / SP, s = i - c * SP;
    float v = 0.f;
    if (s < T) v = xb[c * L + s + 1] - xb[c * L + s];
    dxT[i] = v;
  }
  __syncthreads();
  // exclusive prefix P per channel; PsT[c][63] = S1[c]; P1T[c][s] = P[s+1]
  for (int c = w; c < C; c += 8) {
    float v = (lane > 0) ? dxT[c * SP + lane - 1] : 0.f;
    #pragma unroll
    for (int d = 1; d < 64; d <<= 1) {
      float y = __shfl_up(v, d);
      if (lane >= d) v += y;
    }
    PsT[c * SP + lane] = v;
    if (lane > 0) P1T[c * SP + lane - 1] = v;
    if (lane == 63) P1T[c * SP + 63] = v;   // k=63 product is 0 anyway (dx=0)
  }
  __syncthreads();

  // ---- A-build only (t<100): serial s2 chain -> Ab (V2), Ub (U2) ----
  if (t < 100) {
    const int i_ = t / 10, j_ = t - (t / 10) * 10;
    const float* dip = dxT + i_ * SP;
    const float* pp  = PsT + i_ * SP;
    const float* djp = dxT + j_ * SP;
    float s2 = 0.f;
    #pragma unroll
    for (int ch = 0; ch < 8; ++ch) {
      f4 d0 = *(const f4*)(dip + ch * 8), d1 = *(const f4*)(dip + ch * 8 + 4);
      f4 p0 = *(const f4*)(pp  + ch * 8), p1 = *(const f4*)(pp  + ch * 8 + 4);
      f4 e0 = *(const f4*)(djp + ch * 8), e1 = *(const f4*)(djp + ch * 8 + 4);
      float di[8] = {d0.x, d0.y, d0.z, d0.w, d1.x, d1.y, d1.z, d1.w};
      float pv[8] = {p0.x, p0.y, p0.z, p0.w, p1.x, p1.y, p1.z, p1.w};
      float dj[8] = {e0.x, e0.y, e0.z, e0.w, e1.x, e1.y, e1.z, e1.w};
      float bu[8], bv[8], zz[8];
      #pragma unroll
      for (int e = 0; e < 8; ++e) {            // pointwise (s=63: all zero)
        bu[e] = fmaf(di[e], 0.25f, pv[e]) * (dj[e] * (1.f / 3.f));
        bv[e] = fmaf(di[e], (1.f / 3.f), pv[e]) * (dj[e] * 0.5f);
        zz[e] = fmaf(di[e], 0.5f, pv[e]) * dj[e];
      }
      float u2v[8], v2v[8];
      #pragma unroll
      for (int e = 0; e < 8; ++e) {            // serial: 1 dependent add/step
        u2v[e] = bu[e] + s2;
        v2v[e] = bv[e] + s2;
        s2 += zz[e];
      }
      uint4v vp, up;
      #pragma unroll
      for (int q = 0; q < 4; ++q) {
        vp[q] = packbf(v2v[2 * q], v2v[2 * q + 1]);
        up[q] = packbf(u2v[2 * q], u2v[2 * q + 1]);
      }
      *(uint4v*)&Ab[swz(t, ch * 8)] = vp;
      *(uint4v*)&Ub[swz(t, ch * 8)] = up;
    }
    ob[10 + t] = s2;                           // S2 (fp32)
    if (j_ == 0) ob[i_] = PsT[i_ * SP + 63];   // S1
  }
  __syncthreads();

  // ---- GEMM: wave w owns B column-strip [w*16, w*16+16) ----
  if (w < 7) {
    const int lm = lane & 15, lg = lane >> 4;
    const int bcol = w * 16 + lm;              // this lane's B column
    frag_cast B00, B01, B10, B11;
    B00.u = uint4v{0, 0, 0, 0}; B01.u = uint4v{0, 0, 0, 0};
    B10.u = uint4v{0, 0, 0, 0}; B11.u = uint4v{0, 0, 0, 0};
    if (bcol < 100) {
      const int k2 = bcol / 10, l2 = bcol - (bcol / 10) * 10;
      const float* dk = dxT + k2 * SP;
      const float* dl = dxT + l2 * SP;
      const float* p1 = P1T + l2 * SP;
      const float S1l = PsT[l2 * SP + 63];
      f4 q0 = *(const f4*)(dk + lg * 8),      q1 = *(const f4*)(dk + lg * 8 + 4);
      f4 q2 = *(const f4*)(dk + 32 + lg * 8), q3 = *(const f4*)(dk + 32 + lg * 8 + 4);
      f4 r0 = *(const f4*)(p1 + lg * 8),      r1 = *(const f4*)(p1 + lg * 8 + 4);
      f4 r2 = *(const f4*)(p1 + 32 + lg * 8), r3 = *(const f4*)(p1 + 32 + lg * 8 + 4);
      f4 s0 = *(const f4*)(dl + lg * 8),      s1 = *(const f4*)(dl + lg * 8 + 4);
      f4 s2v = *(const f4*)(dl + 32 + lg * 8), s3 = *(const f4*)(dl + 32 + lg * 8 + 4);
      B00.u = uint4v{packbf(q0.x * (S1l - r0.x), q0.y * (S1l - r0.y)),
                     packbf(q0.z * (S1l - r0.z), q0.w * (S1l - r0.w)),
                     packbf(q1.x * (S1l - r1.x), q1.y * (S1l - r1.y)),
                     packbf(q1.z * (S1l - r1.z), q1.w * (S1l - r1.w))};
      B01.u = uint4v{packbf(q2.x * (S1l - r2.x), q2.y * (S1l - r2.y)),
                     packbf(q2.z * (S1l - r2.z), q2.w * (S1l - r2.w)),
                     packbf(q3.x * (S1l - r3.x), q3.y * (S1l - r3.y)),
                     packbf(q3.z * (S1l - r3.z), q3.w * (S1l - r3.w))};
      B10.u = uint4v{packbf(q0.x * s0.x * 0.5f, q0.y * s0.y * 0.5f),
                     packbf(q0.z * s0.z * 0.5f, q0.w * s0.w * 0.5f),
                     packbf(q1.x * s1.x * 0.5f, q1.y * s1.y * 0.5f),
                     packbf(q1.z * s1.z * 0.5f, q1.w * s1.w * 0.5f)};
      B11.u = uint4v{packbf(q2.x * s2v.x * 0.5f, q2.y * s2v.y * 0.5f),
                     packbf(q2.z * s2v.z * 0.5f, q2.w * s2v.w * 0.5f),
                     packbf(q3.x * s3.x * 0.5f, q3.y * s3.y * 0.5f),
                     packbf(q3.z * s3.z * 0.5f, q3.w * s3.w * 0.5f)};
    } else if (bcol < 110) {                   // S3 columns: B0=dx, B1=0
      const float* dk = dxT + (bcol - 100) * SP;
      f4 q0 = *(const f4*)(dk + lg * 8),      q1 = *(const f4*)(dk + lg * 8 + 4);
      f4 q2 = *(const f4*)(dk + 32 + lg * 8), q3 = *(const f4*)(dk + 32 + lg * 8 + 4);
      B00.u = uint4v{packbf(q0.x, q0.y), packbf(q0.z, q0.w),
                     packbf(q1.x, q1.y), packbf(q1.z, q1.w)};
      B01.u = uint4v{packbf(q2.x, q2.y), packbf(q2.z, q2.w),
                     packbf(q3.x, q3.y), packbf(q3.z, q3.w)};
    }

    const int colbase = w * 16 + lg * 4;       // this lane's 4 output cols
    const short8 zf = {0, 0, 0, 0, 0, 0, 0, 0};
    #pragma unroll 1
    for (int rt = 0; rt < 7; ++rt) {
      const int arow = rt * 16 + lm;
      short8 aV0 = (arow < 100) ? *(const short8*)&Ab[swz(arow, lg * 8)] : zf;
      short8 aV1 = (arow < 100) ? *(const short8*)&Ab[swz(arow, 32 + lg * 8)] : zf;
      short8 aU0 = (arow < 100) ? *(const short8*)&Ub[swz(arow, lg * 8)] : zf;
      short8 aU1 = (arow < 100) ? *(const short8*)&Ub[swz(arow, 32 + lg * 8)] : zf;
      f32x4 acc = {0.f, 0.f, 0.f, 0.f};
      acc = __builtin_amdgcn_mfma_f32_16x16x32_bf16(B00.s, aV0, acc, 0, 0, 0);
      acc = __builtin_amdgcn_mfma_f32_16x16x32_bf16(B01.s, aV1, acc, 0, 0, 0);
      acc = __builtin_amdgcn_mfma_f32_16x16x32_bf16(B10.s, aU0, acc, 0, 0, 0);
      acc = __builtin_amdgcn_mfma_f32_16x16x32_bf16(B11.s, aU1, acc, 0, 0, 0);

      const int row = rt * 16 + lm;            // out row; cols = colbase..+3
      if (row < 100) {
        f2 lo2 = {acc[0], acc[1]};
        f2 hi2 = {acc[2], acc[3]};
        if (colbase < 100) {
          float* rowp4 = ob + 1110 + row * 100;
          *(f2*)(rowp4 + colbase) = lo2;
          *(f2*)(rowp4 + colbase + 2) = hi2;
        } else if (colbase < 110) {            // 100/104/108 -> S3
          float* rowp3 = ob + 110 + row * 10;
          *(f2*)(rowp3 + (colbase - 100)) = lo2;
          if (colbase < 108) *(f2*)(rowp3 + (colbase - 98)) = hi2;
        }
      }
    }
  }
}

extern "C" void kernel_launch(void* const* d_in, const int* in_sizes, int n_in,
                              void* d_out, int out_size, void* d_ws, size_t ws_size,
                              hipStream_t stream) {
  const float* x = (const float*)d_in[0];
  float* out = (float*)d_out;
  const int batch = in_sizes[0] / (C * L);   // 2048
  sig4_kernel<<<dim3(batch), dim3(512), 0, stream>>>(x, out);
}

// Round 27
// 29.148 us; speedup vs baseline: 1.3656x; 1.0524x over previous
//
#include <hip/hip_runtime.h>
#include <hip/hip_bf16.h>

// Depth-4 path signature, C=10, L=64, B=2048 — MFMA formulation (R27).
// Closed form (validated R8-R25, absmax 5.25 vs thr 12.16):
//   P_t = exclusive prefix of dx;  R_t[l] = S1[l] - P_{t+1}[l]
//   per (i,j): s2 serial chain; u2_t, v2_t level-2 scalars
//   S4[ij,kl] = sum_t v2_t*(dx_t[k]*R_t[l]) + sum_t u2_t*(dx_t[k]*dx_t[l]/2)
//   S3[ij,k]  = sum_t v2_t*dx_t[k]
// R27 = R26 with the sign bug fixed: dx = x[s+1]-x[s] = xn - xv DIRECTLY
// (R26's "dx = -dx" flip was wrong — it inverted every odd power of dx).
// Structure (vs R25 best, 30.7us): TWO barriers (was 3).
//  (1) merged stage+scan: each wave loads its channel's 64 path floats from
//      global (coalesced 256B), forms dx via shfl in-register, scans, writes
//      dxT/PsT/P1T in ONE phase. Channel map c = 7-w puts the extra channels
//      on waves 6,7 (not the A-build waves 0,1).
//  (2) B-fragment compute hoisted BEFORE the A-build barrier (needs only
//      dxT/PsT/P1T); GEMM needs Ab/Ub -> single barrier between.
// Canary: absmax must return EXACTLY 5.25 (same FP sequence as R25).

typedef short short8 __attribute__((ext_vector_type(8)));
typedef float f2 __attribute__((ext_vector_type(2)));
typedef float f4 __attribute__((ext_vector_type(4)));
typedef float f32x4 __attribute__((ext_vector_type(4)));
typedef unsigned int uint4v __attribute__((ext_vector_type(4)));

constexpr int C = 10, L = 64, T = 63;          // T = L-1 steps
constexpr int OUTSZ = 10 + 100 + 1000 + 10000; // 11110
constexpr int SP = 68;                         // dxT/PsT/P1T row stride (fp32)
constexpr int KS = 64;                         // A row stride in shorts (128B)

__device__ __forceinline__ unsigned packbf(float lo, float hi) {  // v_cvt_pk_bf16_f32
  union { __hip_bfloat162 h; unsigned u; } cv;
  cv.h = __float22bfloat162_rn(make_float2(lo, hi));
  return cv.u;
}
__device__ __forceinline__ int swz(int row, int k) {  // short idx, 16B-granule XOR
  return row * KS + ((((k >> 3) ^ (row & 7)) << 3) | (k & 7));
}
union frag_cast { uint4v u; short8 s; };

__global__ __launch_bounds__(512, 8) void sig4_kernel(
    const float* __restrict__ x, float* __restrict__ out)
{
  __shared__ __align__(16) unsigned char smem_raw[33760];
  unsigned short* Ab = (unsigned short*)smem_raw;            // V2: 12800B
  unsigned short* Ub = (unsigned short*)(smem_raw + 12800);  // U2: 12800B
  float* dxT = (float*)(smem_raw + 25600);                   // 10*68 f = 2720B
  float* PsT = (float*)(smem_raw + 28320);                   // 2720B
  float* P1T = (float*)(smem_raw + 31040);                   // 2720B (P[s+1])

  const int t = threadIdx.x;
  const int w = t >> 6, lane = t & 63;
  const float* __restrict__ xb = x + (size_t)blockIdx.x * (C * L);
  float* __restrict__ ob = out + (size_t)blockIdx.x * OUTSZ;

  // ---- merged stage+scan: one phase, one barrier ----
  for (int c = 7 - w; c < C; c += 8) {       // waves 6,7 take extra channels
    float xv = xb[c * L + lane];             // coalesced 256B per wave
    float xn = __shfl_down(xv, 1);           // x[lane+1]
    float dx = (lane < T) ? (xn - xv) : 0.f; // dx_s = x[s+1]-x[s]  (FIXED)
    dxT[c * SP + lane] = dx;
    float vprev = __shfl_up(dx, 1);          // dx[lane-1]
    float v = (lane > 0) ? vprev : 0.f;
    #pragma unroll
    for (int d = 1; d < 64; d <<= 1) {       // inclusive scan of shifted dx = excl
      float y = __shfl_up(v, d);
      if (lane >= d) v += y;
    }
    PsT[c * SP + lane] = v;                  // P[lane]; PsT[63] = S1 (dx63=0)
    float p1 = __shfl_down(v, 1);            // P[lane+1]
    if (lane == 63) p1 = v;
    P1T[c * SP + lane] = p1;
  }
  __syncthreads();

  // ---- A-build (t<100, serial s2 chain) ----
  if (t < 100) {
    const int i_ = t / 10, j_ = t - (t / 10) * 10;
    const float* dip = dxT + i_ * SP;
    const float* pp  = PsT + i_ * SP;
    const float* djp = dxT + j_ * SP;
    float s2 = 0.f;
    #pragma unroll
    for (int ch = 0; ch < 8; ++ch) {
      f4 d0 = *(const f4*)(dip + ch * 8), d1 = *(const f4*)(dip + ch * 8 + 4);
      f4 p0 = *(const f4*)(pp  + ch * 8), p1 = *(const f4*)(pp  + ch * 8 + 4);
      f4 e0 = *(const f4*)(djp + ch * 8), e1 = *(const f4*)(djp + ch * 8 + 4);
      float di[8] = {d0.x, d0.y, d0.z, d0.w, d1.x, d1.y, d1.z, d1.w};
      float pv[8] = {p0.x, p0.y, p0.z, p0.w, p1.x, p1.y, p1.z, p1.w};
      float dj[8] = {e0.x, e0.y, e0.z, e0.w, e1.x, e1.y, e1.z, e1.w};
      float bu[8], bv[8], zz[8];
      #pragma unroll
      for (int e = 0; e < 8; ++e) {            // pointwise (s=63: all zero)
        bu[e] = fmaf(di[e], 0.25f, pv[e]) * (dj[e] * (1.f / 3.f));
        bv[e] = fmaf(di[e], (1.f / 3.f), pv[e]) * (dj[e] * 0.5f);
        zz[e] = fmaf(di[e], 0.5f, pv[e]) * dj[e];
      }
      float u2v[8], v2v[8];
      #pragma unroll
      for (int e = 0; e < 8; ++e) {            // serial: 1 dependent add/step
        u2v[e] = bu[e] + s2;
        v2v[e] = bv[e] + s2;
        s2 += zz[e];
      }
      uint4v vp, up;
      #pragma unroll
      for (int q = 0; q < 4; ++q) {
        vp[q] = packbf(v2v[2 * q], v2v[2 * q + 1]);
        up[q] = packbf(u2v[2 * q], u2v[2 * q + 1]);
      }
      *(uint4v*)&Ab[swz(t, ch * 8)] = vp;
      *(uint4v*)&Ub[swz(t, ch * 8)] = up;
    }
    ob[10 + t] = s2;                           // S2 (fp32)
    if (j_ == 0) ob[i_] = PsT[i_ * SP + 63];   // S1
  }

  // ---- B-fragments: before the barrier (needs only dxT/PsT/P1T) ----
  const int lm = lane & 15, lg = lane >> 4;
  frag_cast B00, B01, B10, B11;
  B00.u = uint4v{0, 0, 0, 0}; B01.u = uint4v{0, 0, 0, 0};
  B10.u = uint4v{0, 0, 0, 0}; B11.u = uint4v{0, 0, 0, 0};
  if (w < 7) {
    const int bcol = w * 16 + lm;              // this lane's B column
    if (bcol < 100) {
      const int k2 = bcol / 10, l2 = bcol - (bcol / 10) * 10;
      const float* dk = dxT + k2 * SP;
      const float* dl = dxT + l2 * SP;
      const float* p1 = P1T + l2 * SP;
      const float S1l = PsT[l2 * SP + 63];
      f4 q0 = *(const f4*)(dk + lg * 8),      q1 = *(const f4*)(dk + lg * 8 + 4);
      f4 q2 = *(const f4*)(dk + 32 + lg * 8), q3 = *(const f4*)(dk + 32 + lg * 8 + 4);
      f4 r0 = *(const f4*)(p1 + lg * 8),      r1 = *(const f4*)(p1 + lg * 8 + 4);
      f4 r2 = *(const f4*)(p1 + 32 + lg * 8), r3 = *(const f4*)(p1 + 32 + lg * 8 + 4);
      f4 s0 = *(const f4*)(dl + lg * 8),      s1 = *(const f4*)(dl + lg * 8 + 4);
      f4 s2v = *(const f4*)(dl + 32 + lg * 8), s3 = *(const f4*)(dl + 32 + lg * 8 + 4);
      B00.u = uint4v{packbf(q0.x * (S1l - r0.x), q0.y * (S1l - r0.y)),
                     packbf(q0.z * (S1l - r0.z), q0.w * (S1l - r0.w)),
                     packbf(q1.x * (S1l - r1.x), q1.y * (S1l - r1.y)),
                     packbf(q1.z * (S1l - r1.z), q1.w * (S1l - r1.w))};
      B01.u = uint4v{packbf(q2.x * (S1l - r2.x), q2.y * (S1l - r2.y)),
                     packbf(q2.z * (S1l - r2.z), q2.w * (S1l - r2.w)),
                     packbf(q3.x * (S1l - r3.x), q3.y * (S1l - r3.y)),
                     packbf(q3.z * (S1l - r3.z), q3.w * (S1l - r3.w))};
      B10.u = uint4v{packbf(q0.x * s0.x * 0.5f, q0.y * s0.y * 0.5f),
                     packbf(q0.z * s0.z * 0.5f, q0.w * s0.w * 0.5f),
                     packbf(q1.x * s1.x * 0.5f, q1.y * s1.y * 0.5f),
                     packbf(q1.z * s1.z * 0.5f, q1.w * s1.w * 0.5f)};
      B11.u = uint4v{packbf(q2.x * s2v.x * 0.5f, q2.y * s2v.y * 0.5f),
                     packbf(q2.z * s2v.z * 0.5f, q2.w * s2v.w * 0.5f),
                     packbf(q3.x * s3.x * 0.5f, q3.y * s3.y * 0.5f),
                     packbf(q3.z * s3.z * 0.5f, q3.w * s3.w * 0.5f)};
    } else if (bcol < 110) {                   // S3 columns: B0=dx, B1=0
      const float* dk = dxT + (bcol - 100) * SP;
      f4 q0 = *(const f4*)(dk + lg * 8),      q1 = *(const f4*)(dk + lg * 8 + 4);
      f4 q2 = *(const f4*)(dk + 32 + lg * 8), q3 = *(const f4*)(dk + 32 + lg * 8 + 4);
      B00.u = uint4v{packbf(q0.x, q0.y), packbf(q0.z, q0.w),
                     packbf(q1.x, q1.y), packbf(q1.z, q1.w)};
      B01.u = uint4v{packbf(q2.x, q2.y), packbf(q2.z, q2.w),
                     packbf(q3.x, q3.y), packbf(q3.z, q3.w)};
    }
  }
  __syncthreads();

  // ---- GEMM: wave w owns B column-strip; loop over 7 A row-strips ----
  if (w < 7) {
    const int colbase = w * 16 + lg * 4;       // this lane's 4 output cols
    const short8 zf = {0, 0, 0, 0, 0, 0, 0, 0};
    #pragma unroll 1
    for (int rt = 0; rt < 7; ++rt) {
      const int arow = rt * 16 + lm;
      short8 aV0 = (arow < 100) ? *(const short8*)&Ab[swz(arow, lg * 8)] : zf;
      short8 aV1 = (arow < 100) ? *(const short8*)&Ab[swz(arow, 32 + lg * 8)] : zf;
      short8 aU0 = (arow < 100) ? *(const short8*)&Ub[swz(arow, lg * 8)] : zf;
      short8 aU1 = (arow < 100) ? *(const short8*)&Ub[swz(arow, 32 + lg * 8)] : zf;
      f32x4 acc = {0.f, 0.f, 0.f, 0.f};
      acc = __builtin_amdgcn_mfma_f32_16x16x32_bf16(B00.s, aV0, acc, 0, 0, 0);
      acc = __builtin_amdgcn_mfma_f32_16x16x32_bf16(B01.s, aV1, acc, 0, 0, 0);
      acc = __builtin_amdgcn_mfma_f32_16x16x32_bf16(B10.s, aU0, acc, 0, 0, 0);
      acc = __builtin_amdgcn_mfma_f32_16x16x32_bf16(B11.s, aU1, acc, 0, 0, 0);

      const int row = rt * 16 + lm;            // out row; cols = colbase..+3
      if (row < 100) {
        f2 lo2 = {acc[0], acc[1]};
        f2 hi2 = {acc[2], acc[3]};
        if (colbase < 100) {
          float* rowp4 = ob + 1110 + row * 100;
          *(f2*)(rowp4 + colbase) = lo2;
          *(f2*)(rowp4 + colbase + 2) = hi2;
        } else if (colbase < 110) {            // 100/104/108 -> S3
          float* rowp3 = ob + 110 + row * 10;
          *(f2*)(rowp3 + (colbase - 100)) = lo2;
          if (colbase < 108) *(f2*)(rowp3 + (colbase - 98)) = hi2;
        }
      }
    }
  }
}

extern "C" void kernel_launch(void* const* d_in, const int* in_sizes, int n_in,
                              void* d_out, int out_size, void* d_ws, size_t ws_size,
                              hipStream_t stream) {
  const float* x = (const float*)d_in[0];
  float* out = (float*)d_out;
  const int batch = in_sizes[0] / (C * L);   // 2048
  sig4_kernel<<<dim3(batch), dim3(512), 0, stream>>>(x, out);
}